// Round 7
// baseline (507.437 us; speedup 1.0000x reference)
//
#include <hip/hip_runtime.h>
#include <hip/hip_bf16.h>
#include <math.h>

typedef __hip_bfloat16 bf16;
using s16x8 = __attribute__((ext_vector_type(8))) short;
using f32x4 = __attribute__((ext_vector_type(4))) float;

#define B_ 8
#define C_ 256
#define HW_ 4096
#define TC_ 768     // 3*C
#define NH_ 8
#define CH_ 32      // C/NH
#define HID_ 307
#define HIDP_ 320   // K padded (stage-2 of MLP)
#define HIDM_ 384   // padded rows for w_mlp1 bf16 buffer

__device__ __forceinline__ float ldf(const float* p) { return *p; }
__device__ __forceinline__ float ldf(const bf16* p)  { return __bfloat162float(*p); }
__device__ __forceinline__ void  stf(float* p, float v) { *p = v; }
__device__ __forceinline__ void  stf(bf16* p, float v)  { *p = __float2bfloat16(v); }

__device__ __forceinline__ float bfu2f(unsigned short u) {
    union { unsigned int i; float f; } c; c.i = ((unsigned int)u) << 16; return c.f;
}

__device__ __forceinline__ float gelu_tanh(float u) {
    float c = 0.7978845608028654f * (u + 0.044715f * u * u * u);
    return 0.5f * u * (1.f + tanhf(c));
}

// async global->LDS 16B: dest = lbase + lane*16 (wave-uniform lbase)
__device__ __forceinline__ void stage16(const void* g, uint32_t* lbase, int lane) {
#if __has_builtin(__builtin_amdgcn_global_load_lds)
    __builtin_amdgcn_global_load_lds(
        (const __attribute__((address_space(1))) uint32_t*)g,
        (__attribute__((address_space(3))) uint32_t*)lbase, 16, 0, 0);
#else
    ((uint4*)lbase)[lane] = *(const uint4*)g;
#endif
}

// ---------------------------------------------------------------------------
// MFMA GEMM: out[bt] = act(A[bt] @ Xt[bt]^T + bias) + res[bt]
// A: [M..][Kp] bf16 (K-contig), Xt: [N..][Kp] bf16 (K-contig)
// out: [M][Nld]; writes guarded to n < Nw (and m < M).
// Tile 128x128, BK=64, 4 waves, swizzled LDS (rule 21).
// ---------------------------------------------------------------------------
template <typename TOut>
__global__ __launch_bounds__(256) void mfma_gemm(
    const bf16* __restrict__ A, const bf16* __restrict__ Xt,
    const float* __restrict__ bias, const float* __restrict__ res,
    TOut* __restrict__ out, int M, int Nld, int Nw, int Kp, int act,
    size_t astride, size_t xstride, size_t ostride)
{
    int bt = blockIdx.z;
    A  += (size_t)bt * astride;
    Xt += (size_t)bt * xstride;
    out += (size_t)bt * ostride;
    if (res) res += (size_t)bt * ostride;
    int m0 = blockIdx.y * 128, n0 = blockIdx.x * 128;

    __shared__ uint32_t lds[8192];   // 32 KB

    int tid = threadIdx.x;
    int w = tid >> 6, lane = tid & 63;
    int wr = w >> 1, wc = w & 1;
    int r15 = lane & 15, g = lane >> 4;

    f32x4 zero4 = {0.f, 0.f, 0.f, 0.f};
    f32x4 acc[4][4];
    #pragma unroll
    for (int i = 0; i < 4; i++)
        #pragma unroll
        for (int j = 0; j < 4; j++) acc[i][j] = zero4;

    int nkt = Kp >> 6;
    for (int kt = 0; kt < nkt; kt++) {
        #pragma unroll
        for (int i = 0; i < 4; i++) {
            int row = (w * 4 + i) * 8 + (lane >> 3);   // 0..127
            int us  = (lane & 7) ^ (row & 7);          // source 16B-unit in row
            const bf16* sa = A  + (size_t)(m0 + row) * Kp + kt * 64 + us * 8;
            const bf16* sb = Xt + (size_t)(n0 + row) * Kp + kt * 64 + us * 8;
            stage16(sa, &lds[(w * 4 + i) * 256], lane);
            stage16(sb, &lds[4096 + (w * 4 + i) * 256], lane);
        }
        __syncthreads();

        s16x8 af[4][2], bfr[4][2];
        #pragma unroll
        for (int mm = 0; mm < 4; mm++) {
            int r = wr * 64 + mm * 16 + r15;
            #pragma unroll
            for (int ks = 0; ks < 2; ks++) {
                int u = (ks * 4 + g) ^ (r & 7);
                af[mm][ks] = *(const s16x8*)&lds[(unsigned)(r * 8 + u) * 4];
            }
        }
        #pragma unroll
        for (int nn = 0; nn < 4; nn++) {
            int r = wc * 64 + nn * 16 + r15;
            #pragma unroll
            for (int ks = 0; ks < 2; ks++) {
                int u = (ks * 4 + g) ^ (r & 7);
                bfr[nn][ks] = *(const s16x8*)&lds[4096 + (unsigned)(r * 8 + u) * 4];
            }
        }

        #pragma unroll
        for (int ks = 0; ks < 2; ks++)
            #pragma unroll
            for (int mm = 0; mm < 4; mm++)
                #pragma unroll
                for (int nn = 0; nn < 4; nn++)
                    acc[mm][nn] = __builtin_amdgcn_mfma_f32_16x16x32_bf16(
                        af[mm][ks], bfr[nn][ks], acc[mm][nn], 0, 0, 0);
        __syncthreads();
    }

    #pragma unroll
    for (int mm = 0; mm < 4; mm++) {
        int mbase = m0 + wr * 64 + mm * 16 + g * 4;
        #pragma unroll
        for (int rr = 0; rr < 4; rr++) {
            int m = mbase + rr;
            if (m >= M) continue;
            float bvm = bias ? bias[m] : 0.f;
            #pragma unroll
            for (int nn = 0; nn < 4; nn++) {
                int n = n0 + wc * 64 + nn * 16 + r15;
                if (n >= Nw) continue;
                float v = acc[mm][nn][rr] + bvm;
                if (act == 1) v = gelu_tanh(v);
                if (res) v += res[(size_t)m * Nld + n];
                stf(&out[(size_t)m * Nld + n], v);
            }
        }
    }
}

// ---------------------------------------------------------------------------
// Fused MLP: out = res + W2 @ gelu(W1 @ x2 + b1) + b2  per 64-pixel block.
// x2t: [B][HW][C] bf16 (K-contig); wm1: [384][256]; wm2: [256][320];
// res/out: [B][C][HW] fp32.  grid (HW/64, B), 256 thr (4 waves, 2x2).
// ---------------------------------------------------------------------------
__global__ __launch_bounds__(256) void mlp_fused(
    const bf16* __restrict__ x2t, const bf16* __restrict__ wm1,
    const float* __restrict__ b1, const bf16* __restrict__ wm2,
    const float* __restrict__ b2, const float* __restrict__ res,
    float* __restrict__ out)
{
    int b = blockIdx.y;
    int p0 = blockIdx.x * 64;
    x2t += (size_t)b * HW_ * C_;
    res += (size_t)b * C_ * HW_;
    out += (size_t)b * C_ * HW_;

    __shared__ bf16 h[64][328];     // 41,984 B; pad 328 spreads banks

    int tid = threadIdx.x;
    int w = tid >> 6, lane = tid & 63;
    int wr = w >> 1, wc = w & 1;    // 2x2 wave grid
    int r15 = lane & 15, g = lane >> 4;

    f32x4 zero4 = {0.f, 0.f, 0.f, 0.f};

    // hoist the x2t pixel-tile fragments (reused by all 3 hid-tiles)
    s16x8 bx[8][2];
    #pragma unroll
    for (int kt = 0; kt < 8; kt++)
        #pragma unroll
        for (int nn = 0; nn < 2; nn++) {
            int px = p0 + wc * 32 + nn * 16 + r15;
            bx[kt][nn] = *(const s16x8*)&x2t[(size_t)px * C_ + kt * 32 + g * 8];
        }

    // ---- stage 1: h = gelu(W1 @ x2 + b1), 3 hid-tiles of 128
    #pragma unroll
    for (int mt = 0; mt < 3; mt++) {
        f32x4 acc[4][2];
        #pragma unroll
        for (int mm = 0; mm < 4; mm++)
            #pragma unroll
            for (int nn = 0; nn < 2; nn++) acc[mm][nn] = zero4;

        #pragma unroll
        for (int kt = 0; kt < 8; kt++) {
            s16x8 a[4];
            #pragma unroll
            for (int mm = 0; mm < 4; mm++) {
                int hid = mt * 128 + wr * 64 + mm * 16 + r15;
                a[mm] = *(const s16x8*)&wm1[(size_t)hid * C_ + kt * 32 + g * 8];
            }
            #pragma unroll
            for (int mm = 0; mm < 4; mm++)
                #pragma unroll
                for (int nn = 0; nn < 2; nn++)
                    acc[mm][nn] = __builtin_amdgcn_mfma_f32_16x16x32_bf16(
                        a[mm], bx[kt][nn], acc[mm][nn], 0, 0, 0);
        }
        #pragma unroll
        for (int mm = 0; mm < 4; mm++)
            #pragma unroll
            for (int nn = 0; nn < 2; nn++)
                #pragma unroll
                for (int rr = 0; rr < 4; rr++) {
                    int hid = mt * 128 + wr * 64 + mm * 16 + g * 4 + rr;
                    int px = wc * 32 + nn * 16 + r15;
                    if (hid < HIDP_) {    // FIX: guard LDS width (320); hid 320..383 never read
                        float v = 0.f;
                        if (hid < HID_) v = gelu_tanh(acc[mm][nn][rr] + b1[hid]);
                        h[px][hid] = __float2bfloat16(v);
                    }
                }
    }
    __syncthreads();

    // ---- stage 2: out = res + W2 @ h + b2, 2 C-tiles of 128
    #pragma unroll
    for (int mt = 0; mt < 2; mt++) {
        f32x4 acc[4][2];
        #pragma unroll
        for (int mm = 0; mm < 4; mm++)
            #pragma unroll
            for (int nn = 0; nn < 2; nn++) acc[mm][nn] = zero4;

        #pragma unroll
        for (int kt = 0; kt < 10; kt++) {
            s16x8 a[4], bh[2];
            #pragma unroll
            for (int mm = 0; mm < 4; mm++) {
                int c = mt * 128 + wr * 64 + mm * 16 + r15;
                a[mm] = *(const s16x8*)&wm2[(size_t)c * HIDP_ + kt * 32 + g * 8];
            }
            #pragma unroll
            for (int nn = 0; nn < 2; nn++)
                bh[nn] = *(const s16x8*)&h[wc * 32 + nn * 16 + r15][kt * 32 + g * 8];
            #pragma unroll
            for (int mm = 0; mm < 4; mm++)
                #pragma unroll
                for (int nn = 0; nn < 2; nn++)
                    acc[mm][nn] = __builtin_amdgcn_mfma_f32_16x16x32_bf16(
                        a[mm], bh[nn], acc[mm][nn], 0, 0, 0);
        }
        #pragma unroll
        for (int mm = 0; mm < 4; mm++)
            #pragma unroll
            for (int rr = 0; rr < 4; rr++) {
                int c = mt * 128 + wr * 64 + mm * 16 + g * 4 + rr;
                float bv = b2[c];
                #pragma unroll
                for (int nn = 0; nn < 2; nn++) {
                    int px = p0 + wc * 32 + nn * 16 + r15;
                    out[(size_t)c * HW_ + px] =
                        acc[mm][nn][rr] + bv + res[(size_t)c * HW_ + px];
                }
            }
    }
}

// ---------------------------------------------------------------------------
// Transpose-convert: out[n][r] = bf16(in[r][n]) for r<R else 0.  out: [Ncols][Rpad]
// ---------------------------------------------------------------------------
template <typename TIn>
__global__ __launch_bounds__(256) void transpose_kernel(
    const TIn* __restrict__ in, bf16* __restrict__ out,
    int R, int Ncols, int Rpad, size_t in_z, size_t out_z)
{
    in  += (size_t)blockIdx.z * in_z;
    out += (size_t)blockIdx.z * out_z;
    __shared__ float t[32][33];
    int r0 = blockIdx.y * 32, n0 = blockIdx.x * 32;
    int tx = threadIdx.x & 31, ty = threadIdx.x >> 5;
    #pragma unroll
    for (int s = 0; s < 4; s++) {
        int r = r0 + ty + 8 * s;
        t[ty + 8 * s][tx] = (r < R) ? ldf(&in[(size_t)r * Ncols + n0 + tx]) : 0.f;
    }
    __syncthreads();
    #pragma unroll
    for (int s = 0; s < 4; s++) {
        int n = n0 + ty + 8 * s;
        out[(size_t)n * Rpad + r0 + tx] = __float2bfloat16(t[tx][ty + 8 * s]);
    }
}

// ---------------------------------------------------------------------------
// fp32 [R][Cin] -> bf16 [Rpad][Cout], zero-padded
// ---------------------------------------------------------------------------
__global__ __launch_bounds__(256) void convert_pad_kernel(
    const float* __restrict__ in, bf16* __restrict__ out,
    int R, int Cin, int Cout)
{
    int c = blockIdx.x * 256 + threadIdx.x;
    int r = blockIdx.y;
    if (c >= Cout) return;
    float v = (r < R && c < Cin) ? in[(size_t)r * Cin + c] : 0.f;
    out[(size_t)r * Cout + c] = __float2bfloat16(v);
}

// ---------------------------------------------------------------------------
// Depthwise 3x3, stride 1, pad 1.  One block per 64x64 plane (8 KB), LDS-staged.
// ---------------------------------------------------------------------------
__global__ __launch_bounds__(256) void dwconv_kernel(
    const bf16* __restrict__ in, const float* __restrict__ wdw,
    bf16* __restrict__ out)
{
    int plane = blockIdx.x;              // b*TC + c
    int c = plane % TC_;
    const bf16* ip = in + ((size_t)plane << 12);
    bf16*       op = out + ((size_t)plane << 12);

    __shared__ bf16 sp[64][72];

    int t = threadIdx.x;
    #pragma unroll
    for (int i = 0; i < 2; i++) {
        int px = (t + 256 * i) * 8;
        int r = px >> 6, col = px & 63;
        *(uint4*)&sp[r][col] = *(const uint4*)&ip[px];
    }
    float w[9];
    #pragma unroll
    for (int k = 0; k < 9; k++) w[k] = wdw[c * 9 + k];
    __syncthreads();

    int row = t >> 2, c0 = (t & 3) * 16;
    float acc[16];
    #pragma unroll
    for (int j = 0; j < 16; j++) acc[j] = 0.f;

    #pragma unroll
    for (int dy = -1; dy <= 1; dy++) {
        int yy = row + dy;
        if (yy < 0 || yy > 63) continue;
        float vals[18];
        vals[0]  = (c0 > 0)       ? __bfloat162float(sp[yy][c0 - 1])  : 0.f;
        s16x8 v0 = *(const s16x8*)&sp[yy][c0];
        s16x8 v1 = *(const s16x8*)&sp[yy][c0 + 8];
        #pragma unroll
        for (int j = 0; j < 8; j++) {
            vals[j + 1] = bfu2f((unsigned short)v0[j]);
            vals[j + 9] = bfu2f((unsigned short)v1[j]);
        }
        vals[17] = (c0 + 16 < 64) ? __bfloat162float(sp[yy][c0 + 16]) : 0.f;
        float w0 = w[(dy + 1) * 3], w1 = w[(dy + 1) * 3 + 1], w2 = w[(dy + 1) * 3 + 2];
        #pragma unroll
        for (int j = 0; j < 16; j++)
            acc[j] += w0 * vals[j] + w1 * vals[j + 1] + w2 * vals[j + 2];
    }

    bf16 ob[16];
    #pragma unroll
    for (int j = 0; j < 16; j++) ob[j] = __float2bfloat16(acc[j]);
    #pragma unroll
    for (int i = 0; i < 2; i++)
        *(uint4*)&op[row * 64 + c0 + i * 8] = *(uint4*)&ob[i * 8];
}

__global__ void zero_kernel(float* __restrict__ p, int n)
{
    int i = blockIdx.x * 256 + threadIdx.x;
    if (i < n) p[i] = 0.f;
}

// ---------------------------------------------------------------------------
// Stage A: partial QK^T + partial squared norms per (b,h), chunked over pixels.
// ---------------------------------------------------------------------------
__global__ __launch_bounds__(256) void qk_partial_kernel(
    const bf16* __restrict__ qkv, float* __restrict__ S,
    float* __restrict__ n2q, float* __restrict__ n2k)
{
    int bh = blockIdx.y;
    int b = bh >> 3, h = bh & 7;
    int base = blockIdx.x * 512;
    const bf16* qp = qkv + ((size_t)b * TC_ + h * CH_) * HW_;
    const bf16* kp = qp + (size_t)C_ * HW_;

    __shared__ float qs[32][65], ks[32][65];

    int tid = threadIdx.x;
    int nr = tid >> 3, seg = (tid & 7) * 8;
    float accA[4] = {0.f, 0.f, 0.f, 0.f};
    float sq = 0.f, sk = 0.f;

    for (int t0 = 0; t0 < 512; t0 += 64) {
        #pragma unroll
        for (int i = 0; i < 8; i++) {
            int l = tid + 256 * i;
            int r = l >> 6, cc = l & 63;
            qs[r][cc] = __bfloat162float(qp[(size_t)r * HW_ + base + t0 + cc]);
            ks[r][cc] = __bfloat162float(kp[(size_t)r * HW_ + base + t0 + cc]);
        }
        __syncthreads();
        #pragma unroll
        for (int p = 0; p < 4; p++) {
            int e = tid + 256 * p;
            int i = e >> 5, j = e & 31;
            float s = 0.f;
            #pragma unroll
            for (int kk = 0; kk < 64; kk++) s += qs[i][kk] * ks[j][kk];
            accA[p] += s;
        }
        #pragma unroll
        for (int s = 0; s < 8; s++) {
            float vq = qs[nr][seg + s]; sq += vq * vq;
            float vk = ks[nr][seg + s]; sk += vk * vk;
        }
        __syncthreads();
    }

    #pragma unroll
    for (int off = 1; off < 8; off <<= 1) {
        sq += __shfl_xor(sq, off);
        sk += __shfl_xor(sk, off);
    }
    if ((tid & 7) == 0) {
        atomicAdd(&n2q[bh * 32 + nr], sq);
        atomicAdd(&n2k[bh * 32 + nr], sk);
    }
    #pragma unroll
    for (int p = 0; p < 4; p++) {
        int e = tid + 256 * p;
        atomicAdd(&S[(size_t)bh * 1024 + e], accA[p]);
    }
}

// ---------------------------------------------------------------------------
__global__ __launch_bounds__(64) void softmax_kernel(
    const float* __restrict__ S, const float* __restrict__ n2q,
    const float* __restrict__ n2k, const float* __restrict__ temp,
    float* __restrict__ attnb)
{
    int bh = blockIdx.x, h = bh & 7;
    __shared__ float nkl[32];
    int tid = threadIdx.x;
    if (tid < 32) nkl[tid] = fmaxf(sqrtf(n2k[bh * 32 + tid]), 1e-12f);
    __syncthreads();
    if (tid < 32) {
        float nq = fmaxf(sqrtf(n2q[bh * 32 + tid]), 1e-12f);
        float tp = temp[h];
        float row[32];
        float m = -1e30f;
        #pragma unroll
        for (int j = 0; j < 32; j++) {
            row[j] = S[(size_t)bh * 1024 + tid * 32 + j] * tp / (nq * nkl[j]);
            m = fmaxf(m, row[j]);
        }
        float s = 0.f;
        #pragma unroll
        for (int j = 0; j < 32; j++) { row[j] = expf(row[j] - m); s += row[j]; }
        float inv = 1.f / s;
        #pragma unroll
        for (int j = 0; j < 32; j++)
            attnb[(size_t)bh * 1024 + tid * 32 + j] = row[j] * inv;
    }
}

// ---------------------------------------------------------------------------
__global__ __launch_bounds__(256) void wcomb_kernel(
    const float* __restrict__ w_proj, const float* __restrict__ attnb,
    bf16* __restrict__ wcomb)
{
    int bh = blockIdx.x;
    int b = bh >> 3, h = bh & 7;
    __shared__ float at[32][33];
    int tid = threadIdx.x;
    #pragma unroll
    for (int p = 0; p < 4; p++) {
        int e = tid + 256 * p;
        at[e >> 5][e & 31] = attnb[(size_t)bh * 1024 + e];
    }
    __syncthreads();
    int m = tid;
    float wrow[32];
    #pragma unroll
    for (int i = 0; i < 32; i++) wrow[i] = w_proj[(size_t)m * C_ + h * 32 + i];
    #pragma unroll
    for (int j = 0; j < 32; j++) {
        float s = 0.f;
        #pragma unroll
        for (int i = 0; i < 32; i++) s += wrow[i] * at[i][j];
        wcomb[((size_t)b * C_ + m) * C_ + h * 32 + j] = __float2bfloat16(s);
    }
}

// ---------------------------------------------------------------------------
extern "C" void kernel_launch(void* const* d_in, const int* in_sizes, int n_in,
                              void* d_out, int out_size, void* d_ws, size_t ws_size,
                              hipStream_t stream)
{
    const float* x      = (const float*)d_in[0];
    const float* w_qkv  = (const float*)d_in[1];
    const float* w_dw   = (const float*)d_in[2];
    const float* temp   = (const float*)d_in[3];
    const float* w_proj = (const float*)d_in[4];
    const float* w_mlp1 = (const float*)d_in[5];
    const float* b_mlp1 = (const float*)d_in[6];
    const float* w_mlp2 = (const float*)d_in[7];
    const float* b_mlp2 = (const float*)d_in[8];

    char* ws = (char*)d_ws;
    bf16*  qkv_pre = (bf16*)ws;
    bf16*  xt      = (bf16*)(ws + (size_t)50331648);
    bf16*  wqkv_bf = (bf16*)(ws + (size_t)67108864);
    bf16*  qkv     = (bf16*)(ws + (size_t)50331648);
    float* x2      = (float*)ws;
    float* S_f     = (float*)(ws + (size_t)33554432);
    float* n2q     = S_f + 65536;
    float* n2k     = n2q + 2048;
    float* attnb   = n2k + 2048;
    bf16*  wcomb   = (bf16*)(ws + (size_t)34095104);
    bf16*  wm1_bf  = (bf16*)(ws + (size_t)35143680);
    bf16*  wm2_bf  = (bf16*)(ws + (size_t)35438592);
    bf16*  vt      = (bf16*)(ws + (size_t)35602432);
    bf16*  x2t     = (bf16*)(ws + (size_t)52379648);

    // 1) weights/inputs to bf16
    convert_pad_kernel<<<dim3(1, TC_), 256, 0, stream>>>(w_qkv, wqkv_bf, TC_, C_, C_);
    transpose_kernel<float><<<dim3(128, 8, B_), 256, 0, stream>>>(
        x, xt, C_, HW_, C_, (size_t)C_ * HW_, (size_t)HW_ * C_);

    // 2) qkv_pre = w_qkv @ x   (M=768, N=4096, K=256)
    mfma_gemm<bf16><<<dim3(32, 6, B_), 256, 0, stream>>>(
        wqkv_bf, xt, nullptr, nullptr, qkv_pre, TC_, HW_, HW_, C_, 0,
        0, (size_t)HW_ * C_, (size_t)TC_ * HW_);

    // 3) qkv = dwconv3x3(qkv_pre)
    dwconv_kernel<<<B_ * TC_, 256, 0, stream>>>(qkv_pre, w_dw, qkv);

    // 4) attention statistics
    zero_kernel<<<(69632 + 255) / 256, 256, 0, stream>>>(S_f, 69632);
    qk_partial_kernel<<<dim3(8, 64), 256, 0, stream>>>(qkv, S_f, n2q, n2k);
    softmax_kernel<<<64, 64, 0, stream>>>(S_f, n2q, n2k, temp, attnb);
    wcomb_kernel<<<64, 256, 0, stream>>>(w_proj, attnb, wcomb);

    // 5) remaining weight converts + v transpose
    convert_pad_kernel<<<dim3(1, HIDM_), 256, 0, stream>>>(w_mlp1, wm1_bf, HID_, C_, C_);
    convert_pad_kernel<<<dim3(2, C_), 256, 0, stream>>>(w_mlp2, wm2_bf, C_, HID_, HIDP_);
    transpose_kernel<bf16><<<dim3(128, 8, B_), 256, 0, stream>>>(
        qkv + (size_t)2 * C_ * HW_, vt, C_, HW_, C_,
        (size_t)TC_ * HW_, (size_t)HW_ * C_);

    // 6) x2 = x + Wcomb[b] @ v   (M=256, N=4096, K=256)
    mfma_gemm<float><<<dim3(32, 2, B_), 256, 0, stream>>>(
        wcomb, vt, nullptr, x, x2, C_, HW_, HW_, C_, 0,
        (size_t)C_ * C_, (size_t)HW_ * C_, (size_t)C_ * HW_);

    // 7) x2t
    transpose_kernel<float><<<dim3(128, 8, B_), 256, 0, stream>>>(
        x2, x2t, C_, HW_, C_, (size_t)C_ * HW_, (size_t)HW_ * C_);

    // 8) fused MLP: out = x2 + W2 @ gelu(W1 @ x2 + b1) + b2
    mlp_fused<<<dim3(HW_ / 64, B_), 256, 0, stream>>>(
        x2t, wm1_bf, b_mlp1, wm2_bf, b_mlp2, x2, (float*)d_out);
}

// Round 8
// 480.068 us; speedup vs baseline: 1.0570x; 1.0570x over previous
//
#include <hip/hip_runtime.h>
#include <hip/hip_bf16.h>
#include <math.h>

typedef __hip_bfloat16 bf16;
using s16x8 = __attribute__((ext_vector_type(8))) short;
using f32x4 = __attribute__((ext_vector_type(4))) float;

#define B_ 8
#define C_ 256
#define HW_ 4096
#define TC_ 768     // 3*C
#define NH_ 8
#define CH_ 32      // C/NH
#define HID_ 307
#define HIDP_ 320   // padded hidden (K of mlp2 / N-write of mlp1)
#define HIDM_ 384   // padded rows for w_mlp1 bf16 buffer

__device__ __forceinline__ float ldf(const float* p) { return *p; }
__device__ __forceinline__ float ldf(const bf16* p)  { return __bfloat162float(*p); }
__device__ __forceinline__ void  stf(float* p, float v) { *p = v; }
__device__ __forceinline__ void  stf(bf16* p, float v)  { *p = __float2bfloat16(v); }

__device__ __forceinline__ float bfu2f(unsigned short u) {
    union { unsigned int i; float f; } c; c.i = ((unsigned int)u) << 16; return c.f;
}

__device__ __forceinline__ float gelu_tanh(float u) {
    float c = 0.7978845608028654f * (u + 0.044715f * u * u * u);
    return 0.5f * u * (1.f + tanhf(c));
}

// async global->LDS 16B: dest = lbase + lane*16 (wave-uniform lbase)
__device__ __forceinline__ void stage16(const void* g, uint32_t* lbase, int lane) {
#if __has_builtin(__builtin_amdgcn_global_load_lds)
    __builtin_amdgcn_global_load_lds(
        (const __attribute__((address_space(1))) uint32_t*)g,
        (__attribute__((address_space(3))) uint32_t*)lbase, 16, 0, 0);
#else
    ((uint4*)lbase)[lane] = *(const uint4*)g;
#endif
}

// ---------------------------------------------------------------------------
// MFMA GEMM: out[bt] = act(A[bt] @ Xt[bt]^T + bias) + res[bt]
// A: [M..][Kp] bf16 (K-contig), Xt: [N..][Kp] bf16 (K-contig)
// out: [M][Nld]; writes guarded to n < Nw (and m < M).
// bias_on_n: bias indexed by n (zero past bias_len).
// outT (optional): bf16 transposed copy outT[n*M + m] (for x2t fusion).
// Tile 128x128, BK=64, 4 waves, swizzled LDS (rule 21), 2-phase double-buffer
// prefetch (T3-minimum: stage kt+1 before compute kt; one barrier/iter).
// ---------------------------------------------------------------------------
template <typename TOut>
__global__ __launch_bounds__(256) void mfma_gemm(
    const bf16* __restrict__ A, const bf16* __restrict__ Xt,
    const float* __restrict__ bias, const float* __restrict__ res,
    TOut* __restrict__ out, int M, int Nld, int Nw, int Kp, int act,
    int bias_on_n, int bias_len, bf16* __restrict__ outT,
    size_t astride, size_t xstride, size_t ostride, size_t otstride)
{
    int bt = blockIdx.z;
    A  += (size_t)bt * astride;
    Xt += (size_t)bt * xstride;
    out += (size_t)bt * ostride;
    if (res)  res  += (size_t)bt * ostride;
    if (outT) outT += (size_t)bt * otstride;
    int m0 = blockIdx.y * 128, n0 = blockIdx.x * 128;

    __shared__ uint32_t lds[16384];   // 64 KB: 2 x (A 16KB + B 16KB)

    int tid = threadIdx.x;
    int w = tid >> 6, lane = tid & 63;
    int wr = w >> 1, wc = w & 1;
    int r15 = lane & 15, g = lane >> 4;

    f32x4 zero4 = {0.f, 0.f, 0.f, 0.f};
    f32x4 acc[4][4];
    #pragma unroll
    for (int i = 0; i < 4; i++)
        #pragma unroll
        for (int j = 0; j < 4; j++) acc[i][j] = zero4;

    int nkt = Kp >> 6;
    int srow = (w * 4) * 8 + (lane >> 3);        // this thread's first stage row

    // ---- prologue: stage kt=0 into buf0
    #pragma unroll
    for (int i = 0; i < 4; i++) {
        int row = srow + i * 8;
        int us  = (lane & 7) ^ (row & 7);
        stage16(A  + (size_t)(m0 + row) * Kp + us * 8, &lds[(w * 4 + i) * 256], lane);
        stage16(Xt + (size_t)(n0 + row) * Kp + us * 8, &lds[4096 + (w * 4 + i) * 256], lane);
    }
    asm volatile("s_waitcnt vmcnt(0)" ::: "memory");
    __syncthreads();

    int cur = 0;
    for (int kt = 0; kt < nkt; kt++) {
        int nb = cur ^ 1;
        // ---- issue next tile's stage FIRST (overlaps with compute below)
        if (kt + 1 < nkt) {
            #pragma unroll
            for (int i = 0; i < 4; i++) {
                int row = srow + i * 8;
                int us  = (lane & 7) ^ (row & 7);
                stage16(A  + (size_t)(m0 + row) * Kp + (kt + 1) * 64 + us * 8,
                        &lds[nb * 8192 + (w * 4 + i) * 256], lane);
                stage16(Xt + (size_t)(n0 + row) * Kp + (kt + 1) * 64 + us * 8,
                        &lds[nb * 8192 + 4096 + (w * 4 + i) * 256], lane);
            }
        }

        // ---- fragment reads (swizzled) from buf cur
        const uint32_t* la = &lds[cur * 8192];
        const uint32_t* lb = &lds[cur * 8192 + 4096];
        s16x8 af[4][2], bfr[4][2];
        #pragma unroll
        for (int mm = 0; mm < 4; mm++) {
            int r = wr * 64 + mm * 16 + r15;
            #pragma unroll
            for (int ks = 0; ks < 2; ks++) {
                int u = (ks * 4 + g) ^ (r & 7);
                af[mm][ks] = *(const s16x8*)&la[(unsigned)(r * 8 + u) * 4];
            }
        }
        #pragma unroll
        for (int nn = 0; nn < 4; nn++) {
            int r = wc * 64 + nn * 16 + r15;
            #pragma unroll
            for (int ks = 0; ks < 2; ks++) {
                int u = (ks * 4 + g) ^ (r & 7);
                bfr[nn][ks] = *(const s16x8*)&lb[(unsigned)(r * 8 + u) * 4];
            }
        }

        #pragma unroll
        for (int ks = 0; ks < 2; ks++)
            #pragma unroll
            for (int mm = 0; mm < 4; mm++)
                #pragma unroll
                for (int nn = 0; nn < 4; nn++)
                    acc[mm][nn] = __builtin_amdgcn_mfma_f32_16x16x32_bf16(
                        af[mm][ks], bfr[nn][ks], acc[mm][nn], 0, 0, 0);

        if (kt + 1 < nkt) {
            asm volatile("s_waitcnt vmcnt(0)" ::: "memory");
            __syncthreads();
        }
        cur = nb;
    }

    // ---- epilogue
    #pragma unroll
    for (int mm = 0; mm < 4; mm++) {
        int mbase = m0 + wr * 64 + mm * 16 + g * 4;
        #pragma unroll
        for (int rr = 0; rr < 4; rr++) {
            int m = mbase + rr;
            if (m >= M) continue;
            float bvm = (bias && !bias_on_n) ? bias[m] : 0.f;
            #pragma unroll
            for (int nn = 0; nn < 4; nn++) {
                int n = n0 + wc * 64 + nn * 16 + r15;
                if (n >= Nw) continue;
                float bv = bias_on_n ? ((bias && n < bias_len) ? bias[n] : 0.f) : bvm;
                float v = acc[mm][nn][rr] + bv;
                if (act == 1) v = gelu_tanh(v);
                if (res) v += res[(size_t)m * Nld + n];
                stf(&out[(size_t)m * Nld + n], v);
                if (outT) outT[(size_t)n * M + m] = __float2bfloat16(v);
            }
        }
    }
}

// ---------------------------------------------------------------------------
// Transpose-convert: out[n][r] = bf16(in[r][n]) for r<R else 0.  out: [Ncols][Rpad]
// ---------------------------------------------------------------------------
template <typename TIn>
__global__ __launch_bounds__(256) void transpose_kernel(
    const TIn* __restrict__ in, bf16* __restrict__ out,
    int R, int Ncols, int Rpad, size_t in_z, size_t out_z)
{
    in  += (size_t)blockIdx.z * in_z;
    out += (size_t)blockIdx.z * out_z;
    __shared__ float t[32][33];
    int r0 = blockIdx.y * 32, n0 = blockIdx.x * 32;
    int tx = threadIdx.x & 31, ty = threadIdx.x >> 5;
    #pragma unroll
    for (int s = 0; s < 4; s++) {
        int r = r0 + ty + 8 * s;
        t[ty + 8 * s][tx] = (r < R) ? ldf(&in[(size_t)r * Ncols + n0 + tx]) : 0.f;
    }
    __syncthreads();
    #pragma unroll
    for (int s = 0; s < 4; s++) {
        int n = n0 + ty + 8 * s;
        out[(size_t)n * Rpad + r0 + tx] = __float2bfloat16(t[tx][ty + 8 * s]);
    }
}

// ---------------------------------------------------------------------------
// fp32 [R][Cin] -> bf16 [Rpad][Cout], zero-padded
// ---------------------------------------------------------------------------
__global__ __launch_bounds__(256) void convert_pad_kernel(
    const float* __restrict__ in, bf16* __restrict__ out,
    int R, int Cin, int Cout)
{
    int c = blockIdx.x * 256 + threadIdx.x;
    int r = blockIdx.y;
    if (c >= Cout) return;
    float v = (r < R && c < Cin) ? in[(size_t)r * Cin + c] : 0.f;
    out[(size_t)r * Cout + c] = __float2bfloat16(v);
}

// ---------------------------------------------------------------------------
// Depthwise 3x3, stride 1, pad 1.  One block per 64x64 plane (8 KB), LDS-staged.
// ---------------------------------------------------------------------------
__global__ __launch_bounds__(256) void dwconv_kernel(
    const bf16* __restrict__ in, const float* __restrict__ wdw,
    bf16* __restrict__ out)
{
    int plane = blockIdx.x;              // b*TC + c
    int c = plane % TC_;
    const bf16* ip = in + ((size_t)plane << 12);
    bf16*       op = out + ((size_t)plane << 12);

    __shared__ bf16 sp[64][72];

    int t = threadIdx.x;
    #pragma unroll
    for (int i = 0; i < 2; i++) {
        int px = (t + 256 * i) * 8;
        int r = px >> 6, col = px & 63;
        *(uint4*)&sp[r][col] = *(const uint4*)&ip[px];
    }
    float w[9];
    #pragma unroll
    for (int k = 0; k < 9; k++) w[k] = wdw[c * 9 + k];
    __syncthreads();

    int row = t >> 2, c0 = (t & 3) * 16;
    float acc[16];
    #pragma unroll
    for (int j = 0; j < 16; j++) acc[j] = 0.f;

    #pragma unroll
    for (int dy = -1; dy <= 1; dy++) {
        int yy = row + dy;
        if (yy < 0 || yy > 63) continue;
        float vals[18];
        vals[0]  = (c0 > 0)       ? __bfloat162float(sp[yy][c0 - 1])  : 0.f;
        s16x8 v0 = *(const s16x8*)&sp[yy][c0];
        s16x8 v1 = *(const s16x8*)&sp[yy][c0 + 8];
        #pragma unroll
        for (int j = 0; j < 8; j++) {
            vals[j + 1] = bfu2f((unsigned short)v0[j]);
            vals[j + 9] = bfu2f((unsigned short)v1[j]);
        }
        vals[17] = (c0 + 16 < 64) ? __bfloat162float(sp[yy][c0 + 16]) : 0.f;
        float w0 = w[(dy + 1) * 3], w1 = w[(dy + 1) * 3 + 1], w2 = w[(dy + 1) * 3 + 2];
        #pragma unroll
        for (int j = 0; j < 16; j++)
            acc[j] += w0 * vals[j] + w1 * vals[j + 1] + w2 * vals[j + 2];
    }

    bf16 ob[16];
    #pragma unroll
    for (int j = 0; j < 16; j++) ob[j] = __float2bfloat16(acc[j]);
    #pragma unroll
    for (int i = 0; i < 2; i++)
        *(uint4*)&op[row * 64 + c0 + i * 8] = *(uint4*)&ob[i * 8];
}

__global__ void zero_kernel(float* __restrict__ p, int n)
{
    int i = blockIdx.x * 256 + threadIdx.x;
    if (i < n) p[i] = 0.f;
}

// ---------------------------------------------------------------------------
// Stage A: partial QK^T + partial squared norms per (b,h), chunked over pixels.
// ---------------------------------------------------------------------------
__global__ __launch_bounds__(256) void qk_partial_kernel(
    const bf16* __restrict__ qkv, float* __restrict__ S,
    float* __restrict__ n2q, float* __restrict__ n2k)
{
    int bh = blockIdx.y;
    int b = bh >> 3, h = bh & 7;
    int base = blockIdx.x * 512;
    const bf16* qp = qkv + ((size_t)b * TC_ + h * CH_) * HW_;
    const bf16* kp = qp + (size_t)C_ * HW_;

    __shared__ float qs[32][65], ks[32][65];

    int tid = threadIdx.x;
    int nr = tid >> 3, seg = (tid & 7) * 8;
    float accA[4] = {0.f, 0.f, 0.f, 0.f};
    float sq = 0.f, sk = 0.f;

    for (int t0 = 0; t0 < 512; t0 += 64) {
        #pragma unroll
        for (int i = 0; i < 8; i++) {
            int l = tid + 256 * i;
            int r = l >> 6, cc = l & 63;
            qs[r][cc] = __bfloat162float(qp[(size_t)r * HW_ + base + t0 + cc]);
            ks[r][cc] = __bfloat162float(kp[(size_t)r * HW_ + base + t0 + cc]);
        }
        __syncthreads();
        #pragma unroll
        for (int p = 0; p < 4; p++) {
            int e = tid + 256 * p;
            int i = e >> 5, j = e & 31;
            float s = 0.f;
            #pragma unroll
            for (int kk = 0; kk < 64; kk++) s += qs[i][kk] * ks[j][kk];
            accA[p] += s;
        }
        #pragma unroll
        for (int s = 0; s < 8; s++) {
            float vq = qs[nr][seg + s]; sq += vq * vq;
            float vk = ks[nr][seg + s]; sk += vk * vk;
        }
        __syncthreads();
    }

    #pragma unroll
    for (int off = 1; off < 8; off <<= 1) {
        sq += __shfl_xor(sq, off);
        sk += __shfl_xor(sk, off);
    }
    if ((tid & 7) == 0) {
        atomicAdd(&n2q[bh * 32 + nr], sq);
        atomicAdd(&n2k[bh * 32 + nr], sk);
    }
    #pragma unroll
    for (int p = 0; p < 4; p++) {
        int e = tid + 256 * p;
        atomicAdd(&S[(size_t)bh * 1024 + e], accA[p]);
    }
}

// ---------------------------------------------------------------------------
__global__ __launch_bounds__(64) void softmax_kernel(
    const float* __restrict__ S, const float* __restrict__ n2q,
    const float* __restrict__ n2k, const float* __restrict__ temp,
    float* __restrict__ attnb)
{
    int bh = blockIdx.x, h = bh & 7;
    __shared__ float nkl[32];
    int tid = threadIdx.x;
    if (tid < 32) nkl[tid] = fmaxf(sqrtf(n2k[bh * 32 + tid]), 1e-12f);
    __syncthreads();
    if (tid < 32) {
        float nq = fmaxf(sqrtf(n2q[bh * 32 + tid]), 1e-12f);
        float tp = temp[h];
        float row[32];
        float m = -1e30f;
        #pragma unroll
        for (int j = 0; j < 32; j++) {
            row[j] = S[(size_t)bh * 1024 + tid * 32 + j] * tp / (nq * nkl[j]);
            m = fmaxf(m, row[j]);
        }
        float s = 0.f;
        #pragma unroll
        for (int j = 0; j < 32; j++) { row[j] = expf(row[j] - m); s += row[j]; }
        float inv = 1.f / s;
        #pragma unroll
        for (int j = 0; j < 32; j++)
            attnb[(size_t)bh * 1024 + tid * 32 + j] = row[j] * inv;
    }
}

// ---------------------------------------------------------------------------
__global__ __launch_bounds__(256) void wcomb_kernel(
    const float* __restrict__ w_proj, const float* __restrict__ attnb,
    bf16* __restrict__ wcomb)
{
    int bh = blockIdx.x;
    int b = bh >> 3, h = bh & 7;
    __shared__ float at[32][33];
    int tid = threadIdx.x;
    #pragma unroll
    for (int p = 0; p < 4; p++) {
        int e = tid + 256 * p;
        at[e >> 5][e & 31] = attnb[(size_t)bh * 1024 + e];
    }
    __syncthreads();
    int m = tid;
    float wrow[32];
    #pragma unroll
    for (int i = 0; i < 32; i++) wrow[i] = w_proj[(size_t)m * C_ + h * 32 + i];
    #pragma unroll
    for (int j = 0; j < 32; j++) {
        float s = 0.f;
        #pragma unroll
        for (int i = 0; i < 32; i++) s += wrow[i] * at[i][j];
        wcomb[((size_t)b * C_ + m) * C_ + h * 32 + j] = __float2bfloat16(s);
    }
}

// ---------------------------------------------------------------------------
extern "C" void kernel_launch(void* const* d_in, const int* in_sizes, int n_in,
                              void* d_out, int out_size, void* d_ws, size_t ws_size,
                              hipStream_t stream)
{
    const float* x      = (const float*)d_in[0];
    const float* w_qkv  = (const float*)d_in[1];
    const float* w_dw   = (const float*)d_in[2];
    const float* temp   = (const float*)d_in[3];
    const float* w_proj = (const float*)d_in[4];
    const float* w_mlp1 = (const float*)d_in[5];
    const float* b_mlp1 = (const float*)d_in[6];
    const float* w_mlp2 = (const float*)d_in[7];
    const float* b_mlp2 = (const float*)d_in[8];

    char* ws = (char*)d_ws;
    bf16*  qkv_pre = (bf16*)ws;                          // dead after dwconv
    bf16*  xt      = (bf16*)(ws + (size_t)50331648);     // dead after GEMM2
    bf16*  wqkv_bf = (bf16*)(ws + (size_t)67108864);     // dead after GEMM2
    bf16*  qkv     = (bf16*)(ws + (size_t)50331648);     // dead after vt build
    float* x2      = (float*)ws;
    float* S_f     = (float*)(ws + (size_t)33554432);
    float* n2q     = S_f + 65536;
    float* n2k     = n2q + 2048;
    float* attnb   = n2k + 2048;
    bf16*  wcomb   = (bf16*)(ws + (size_t)34095104);
    bf16*  wm1_bf  = (bf16*)(ws + (size_t)35143680);
    bf16*  wm2_bf  = (bf16*)(ws + (size_t)35438592);
    bf16*  vt      = (bf16*)(ws + (size_t)35602432);     // overlaps qkv b0 q-rows (safe)
    bf16*  x2t     = (bf16*)(ws + (size_t)52379648);     // [B][HW][C] = [32768][256]
    bf16*  yt      = (bf16*)(ws + (size_t)72400896);     // [32768][320]

    // 1) weights/inputs to bf16
    convert_pad_kernel<<<dim3(1, TC_), 256, 0, stream>>>(w_qkv, wqkv_bf, TC_, C_, C_);
    transpose_kernel<float><<<dim3(128, 8, B_), 256, 0, stream>>>(
        x, xt, C_, HW_, C_, (size_t)C_ * HW_, (size_t)HW_ * C_);

    // 2) qkv_pre = w_qkv @ x   (M=768, N=4096, K=256, per-batch)
    mfma_gemm<bf16><<<dim3(32, 6, B_), 256, 0, stream>>>(
        wqkv_bf, xt, nullptr, nullptr, qkv_pre, TC_, HW_, HW_, C_, 0, 0, 0, nullptr,
        0, (size_t)HW_ * C_, (size_t)TC_ * HW_, 0);

    // 3) qkv = dwconv3x3(qkv_pre)
    dwconv_kernel<<<B_ * TC_, 256, 0, stream>>>(qkv_pre, w_dw, qkv);

    // 4) attention statistics
    zero_kernel<<<(69632 + 255) / 256, 256, 0, stream>>>(S_f, 69632);
    qk_partial_kernel<<<dim3(8, 64), 256, 0, stream>>>(qkv, S_f, n2q, n2k);
    softmax_kernel<<<64, 64, 0, stream>>>(S_f, n2q, n2k, temp, attnb);
    wcomb_kernel<<<64, 256, 0, stream>>>(w_proj, attnb, wcomb);

    // 5) remaining weight converts + v transpose
    convert_pad_kernel<<<dim3(1, HIDM_), 256, 0, stream>>>(w_mlp1, wm1_bf, HID_, C_, C_);
    convert_pad_kernel<<<dim3(2, C_), 256, 0, stream>>>(w_mlp2, wm2_bf, C_, HID_, HIDP_);
    transpose_kernel<bf16><<<dim3(128, 8, B_), 256, 0, stream>>>(
        qkv + (size_t)2 * C_ * HW_, vt, C_, HW_, C_,
        (size_t)TC_ * HW_, (size_t)HW_ * C_);

    // 6) x2 = x + Wcomb[b] @ v  (M=256, N=4096, K=256) — also emits x2t (bf16)
    mfma_gemm<float><<<dim3(32, 2, B_), 256, 0, stream>>>(
        wcomb, vt, nullptr, x, x2, C_, HW_, HW_, C_, 0, 0, 0, x2t,
        (size_t)C_ * C_, (size_t)HW_ * C_, (size_t)C_ * HW_, (size_t)HW_ * C_);

    // 7) yt = gelu(x2t @ wm1^T + b1)  (M=32768 batch-folded, N=384 ld/wr 320, K=256)
    mfma_gemm<bf16><<<dim3(3, 256, 1), 256, 0, stream>>>(
        x2t, wm1_bf, b_mlp1, nullptr, yt, 32768, HIDP_, HIDP_, C_, 1, 1, HID_, nullptr,
        0, 0, 0, 0);

    // 8) out = x2 + wm2 @ y + b2  (M=256, N=4096, K=320, per-batch)
    mfma_gemm<float><<<dim3(32, 2, B_), 256, 0, stream>>>(
        wm2_bf, yt, b_mlp2, x2, (float*)d_out, C_, HW_, HW_, HIDP_, 0, 0, 0, nullptr,
        0, (size_t)HW_ * HIDP_, (size_t)C_ * HW_, 0);
}